// Round 1
// baseline (147.164 us; speedup 1.0000x reference)
//
#include <hip/hip_runtime.h>

// Problem constants (fixed by setup_inputs in the reference).
#define BB 128
#define CC 3
#define HH 224
#define WW 224
#define PP 16

// ---------------------------------------------------------------------------
// Kernel 1 (mask path): scatter mask bytes. One thread per masked pixel.
// tid -> (patch, i, j); patches = B*N. Overlapping patches all write 1: safe.
// ---------------------------------------------------------------------------
__global__ void occl_scatter_mask(unsigned char* __restrict__ mask,
                                  const int* __restrict__ px,
                                  const int* __restrict__ py,
                                  int total, int N) {
    int tid = blockIdx.x * blockDim.x + threadIdx.x;
    if (tid >= total) return;
    int j = tid & (PP - 1);
    int i = (tid >> 4) & (PP - 1);
    int p = tid >> 8;                  // patch index in [0, B*N)
    int b = p / N;
    int x = px[p];                     // H index of patch top-left
    int y = py[p];                     // W index
    mask[(size_t)b * (HH * WW) + (size_t)(x + i) * WW + (y + j)] = 1;
}

// ---------------------------------------------------------------------------
// Kernel 2 (mask path): out = mask ? 0 : imgs, float4-vectorized.
// idx -> (b, c, h, w4). Mask word load is 4B-aligned (W=224, all strides %4==0).
// ---------------------------------------------------------------------------
__global__ void occl_apply(float4* __restrict__ out,
                           const float4* __restrict__ imgs,
                           const unsigned int* __restrict__ mask32,
                           int total4) {
    int idx = blockIdx.x * blockDim.x + threadIdx.x;
    if (idx >= total4) return;
    const int W4 = WW / 4;
    int w4 = idx % W4;
    int t  = idx / W4;
    int h  = t % HH;
    int bc = t / HH;          // b*C + c
    int b  = bc / CC;
    unsigned int m = mask32[(size_t)b * (HH * WW / 4) + h * W4 + w4];
    float4 v = imgs[idx];
    if (m) {
        if (m & 0x000000FFu) v.x = 0.f;
        if (m & 0x0000FF00u) v.y = 0.f;
        if (m & 0x00FF0000u) v.z = 0.f;
        if (m & 0xFF000000u) v.w = 0.f;
    }
    out[idx] = v;
}

// ---------------------------------------------------------------------------
// Fallback path (ws too small): straight copy then scalar zeroing of patches.
// ---------------------------------------------------------------------------
__global__ void occl_copy(float4* __restrict__ out,
                          const float4* __restrict__ in, int total4) {
    int idx = blockIdx.x * blockDim.x + threadIdx.x;
    if (idx < total4) out[idx] = in[idx];
}

__global__ void occl_zero_patches(float* __restrict__ out,
                                  const int* __restrict__ px,
                                  const int* __restrict__ py,
                                  int total, int N) {
    int tid = blockIdx.x * blockDim.x + threadIdx.x;
    if (tid >= total) return;
    int j = tid & (PP - 1);
    int i = (tid >> 4) & (PP - 1);
    int t = tid >> 8;          // (patch, c)
    int c = t % CC;
    int p = t / CC;
    int b = p / N;
    int x = px[p];
    int y = py[p];
    size_t off = (((size_t)b * CC + c) * HH + (x + i)) * (size_t)WW + (y + j);
    out[off] = 0.f;
}

extern "C" void kernel_launch(void* const* d_in, const int* in_sizes, int n_in,
                              void* d_out, int out_size, void* d_ws, size_t ws_size,
                              hipStream_t stream) {
    const float* imgs = (const float*)d_in[0];
    const int*   px   = (const int*)d_in[1];
    const int*   py   = (const int*)d_in[2];
    float*       out  = (float*)d_out;

    const int N        = in_sizes[1] / BB;   // points per image (98)
    const int nPatches = BB * N;
    const size_t maskBytes = (size_t)BB * HH * WW;   // 6.42 MB

    if (ws_size >= maskBytes) {
        // 1) zero the byte mask (ws is poisoned to 0xAA before every call)
        hipMemsetAsync(d_ws, 0, maskBytes, stream);

        // 2) scatter patch bytes
        int totalScatter = nPatches * PP * PP;
        int blks = (totalScatter + 255) / 256;
        occl_scatter_mask<<<blks, 256, 0, stream>>>(
            (unsigned char*)d_ws, px, py, totalScatter, N);

        // 3) masked copy, float4-wide
        int total4 = out_size / 4;
        blks = (total4 + 255) / 256;
        occl_apply<<<blks, 256, 0, stream>>>(
            (float4*)out, (const float4*)imgs, (const unsigned int*)d_ws, total4);
    } else {
        int total4 = out_size / 4;
        int blks = (total4 + 255) / 256;
        occl_copy<<<blks, 256, 0, stream>>>((float4*)out, (const float4*)imgs, total4);

        int totalZero = nPatches * CC * PP * PP;
        blks = (totalZero + 255) / 256;
        occl_zero_patches<<<blks, 256, 0, stream>>>(out, px, py, totalZero, N);
    }
}

// Round 2
// 143.953 us; speedup vs baseline: 1.0223x; 1.0223x over previous
//
#include <hip/hip_runtime.h>

// Problem constants (fixed by setup_inputs in the reference).
#define BB 128
#define CC 3
#define HH 224
#define WW 224
#define PP 16

#define W4 (WW / 4)              // 56 float4 per row
#define PER_IMG4 (CC * HH * W4)  // 37632 float4 per image
#define NCHUNK 7                 // 37632 / 7 = 5376 = 256 * 21 (exact)
#define NWORDS (HH * 7)          // 224 rows * 7 words of row-bitmask = 1568

// One block = (image b, chunk x). Build the image's 224x224 occlusion bitmask
// in LDS (6272 B), then masked-copy this block's 1/7 slice of the image.
// Overlapping patches are handled by atomicOr; mask build overlaps with the
// streaming copy across the many resident waves.
__global__ __launch_bounds__(256) void occl_fused(
        float4* __restrict__ out, const float4* __restrict__ imgs,
        const int* __restrict__ px, const int* __restrict__ py, int N) {
    __shared__ unsigned int rowbits[NWORDS];
    const int t = threadIdx.x;
    const int b = blockIdx.y;

    // 1) zero the bitmask (6.1 words/thread)
    for (int i = t; i < NWORDS; i += 256) rowbits[i] = 0u;
    __syncthreads();

    // 2) scatter this image's patches: one row-segment of 16 bits per task
    const int nrow = N * PP;  // 1568 row-segments
    for (int r = t; r < nrow; r += 256) {
        int p = r >> 4;            // patch index
        int i = r & (PP - 1);      // row within patch
        int x = px[b * N + p] + i; // H index of this row
        int y = py[b * N + p];     // W start bit
        unsigned long long mm = 0xFFFFull << (y & 31);
        int w0 = x * 7 + (y >> 5);
        atomicOr(&rowbits[w0], (unsigned int)mm);
        unsigned int hi = (unsigned int)(mm >> 32);
        if (hi) atomicOr(&rowbits[w0 + 1], hi);
    }
    __syncthreads();

    // 3) masked streaming copy of this block's slice (exact, no bounds check)
    const int chunk = PER_IMG4 / NCHUNK;  // 5376
    int base = blockIdx.x * chunk;
    const float4* __restrict__ src = imgs + (size_t)b * PER_IMG4;
    float4* __restrict__ dst = out + (size_t)b * PER_IMG4;
#pragma unroll 3
    for (int k = 0; k < chunk / 256; ++k) {
        int f = base + k * 256 + t;
        int w4 = f % W4;                 // float4 column
        int hh = (f / W4) % HH;          // row (channel doesn't affect mask)
        unsigned int word = rowbits[hh * 7 + (w4 >> 3)];
        unsigned int m4 = (word >> ((w4 & 7) * 4)) & 0xFu;
        float4 v = src[f];
        if (m4) {
            if (m4 & 1u) v.x = 0.f;
            if (m4 & 2u) v.y = 0.f;
            if (m4 & 4u) v.z = 0.f;
            if (m4 & 8u) v.w = 0.f;
        }
        dst[f] = v;
    }
}

extern "C" void kernel_launch(void* const* d_in, const int* in_sizes, int n_in,
                              void* d_out, int out_size, void* d_ws, size_t ws_size,
                              hipStream_t stream) {
    const float* imgs = (const float*)d_in[0];
    const int*   px   = (const int*)d_in[1];
    const int*   py   = (const int*)d_in[2];
    float*       out  = (float*)d_out;

    const int N = in_sizes[1] / BB;  // points per image (98)

    dim3 grid(NCHUNK, BB);           // 7 x 128 = 896 blocks
    occl_fused<<<grid, 256, 0, stream>>>(
        (float4*)out, (const float4*)imgs, px, py, N);
}

// Round 4
// 139.330 us; speedup vs baseline: 1.0562x; 1.0332x over previous
//
#include <hip/hip_runtime.h>

// Problem constants (fixed by setup_inputs in the reference).
#define BB 128
#define CC 3
#define HH 224
#define WW 224
#define PP 16

#define W4 (WW / 4)               // 56 float4 per row
#define PER_IMG4 (CC * HH * W4)   // 37632 float4 per image
#define NWORDS (HH * 7)           // 224 rows * 7 words = 1568 words = 6272 B/img
#define TOTAL4 (BB * PER_IMG4)    // 4,816,896 float4 total

typedef float vfloat4 __attribute__((ext_vector_type(4)));  // native vec for NT builtins

// ---------------------------------------------------------------------------
// Kernel A: one block per image. Build the 224x224 occlusion bitmask in LDS
// (atomicOr handles overlapping patches), then dump 1568 words to global ws.
// Total global mask = 128 * 6272 B = 784 KB -> stays hot in L2 for kernel B.
// ---------------------------------------------------------------------------
__global__ __launch_bounds__(256) void occl_build(
        unsigned int* __restrict__ gmask,
        const int* __restrict__ px, const int* __restrict__ py, int N) {
    __shared__ unsigned int rowbits[NWORDS];
    const int t = threadIdx.x;
    const int b = blockIdx.x;

    for (int i = t; i < NWORDS; i += 256) rowbits[i] = 0u;
    __syncthreads();

    const int nrow = N * PP;  // 1568 row-segments (one 16-bit run each)
    for (int r = t; r < nrow; r += 256) {
        int p = r >> 4;             // patch index
        int i = r & (PP - 1);       // row within patch
        int x = px[b * N + p] + i;  // H index of this row
        int y = py[b * N + p];      // W start bit (y+16 <= 224, stays in-row)
        unsigned long long mm = 0xFFFFull << (y & 31);
        int w0 = x * 7 + (y >> 5);
        atomicOr(&rowbits[w0], (unsigned int)mm);
        unsigned int hi = (unsigned int)(mm >> 32);
        if (hi) atomicOr(&rowbits[w0 + 1], hi);
    }
    __syncthreads();

    unsigned int* dst = gmask + (size_t)b * NWORDS;
    for (int i = t; i < NWORDS; i += 256) dst[i] = rowbits[i];
}

// ---------------------------------------------------------------------------
// Kernel B: pure streaming masked copy. One float4 per thread, exact grid
// (18816 blocks -> full occupancy, no bounds check). Mask word comes from
// the 784 KB global mask (L2-resident). Nontemporal store keeps L2 for reads.
// ---------------------------------------------------------------------------
__global__ __launch_bounds__(256) void occl_apply(
        vfloat4* __restrict__ out, const vfloat4* __restrict__ imgs,
        const unsigned int* __restrict__ gmask) {
    int f = blockIdx.x * 256 + threadIdx.x;   // [0, TOTAL4), exact
    int w4 = f % W4;                          // float4 column
    int t  = f / W4;
    int h  = t % HH;                          // row
    int b  = t / (HH * CC);                   // image (channel drops out)
    unsigned int word = gmask[(size_t)b * NWORDS + h * 7 + (w4 >> 3)];
    unsigned int m4 = (word >> ((w4 & 7) * 4)) & 0xFu;
    vfloat4 v = imgs[f];
    if (m4 & 1u) v.x = 0.f;
    if (m4 & 2u) v.y = 0.f;
    if (m4 & 4u) v.z = 0.f;
    if (m4 & 8u) v.w = 0.f;
    __builtin_nontemporal_store(v, &out[f]);
}

extern "C" void kernel_launch(void* const* d_in, const int* in_sizes, int n_in,
                              void* d_out, int out_size, void* d_ws, size_t ws_size,
                              hipStream_t stream) {
    const float* imgs = (const float*)d_in[0];
    const int*   px   = (const int*)d_in[1];
    const int*   py   = (const int*)d_in[2];
    float*       out  = (float*)d_out;

    const int N = in_sizes[1] / BB;  // points per image (98)

    occl_build<<<BB, 256, 0, stream>>>((unsigned int*)d_ws, px, py, N);
    occl_apply<<<TOTAL4 / 256, 256, 0, stream>>>(
        (vfloat4*)out, (const vfloat4*)imgs, (const unsigned int*)d_ws);
}

// Round 5
// 137.688 us; speedup vs baseline: 1.0688x; 1.0119x over previous
//
#include <hip/hip_runtime.h>

// Problem constants (fixed by setup_inputs in the reference).
#define BB 128
#define CC 3
#define HH 224
#define WW 224
#define PP 16

#define W4 (WW / 4)               // 56 float4 per row
#define CHAN4 (HH * W4)           // 12544 float4 per channel = 49 * 256 (exact!)
#define PER_IMG4 (CC * CHAN4)     // 37632 float4 per image
#define TOTAL4 (BB * PER_IMG4)    // 4,816,896 float4 total
#define NROWS 6                   // 256 float4 span at most 6 image rows

typedef float vfloat4 __attribute__((ext_vector_type(4)));

// ---------------------------------------------------------------------------
// Fully fused: each 256-thread block owns 256 consecutive float4 (never
// crossing a channel boundary), builds a 42-word LDS bitmask for its <=6-row
// window directly from the point list (~9 intersecting patches/block), then
// does the masked streaming copy. No global mask, no second kernel.
// ---------------------------------------------------------------------------
__global__ __launch_bounds__(256) void occl_fused(
        vfloat4* __restrict__ out, const vfloat4* __restrict__ imgs,
        const int* __restrict__ px, const int* __restrict__ py, int N) {
    const int t = threadIdx.x;
    const int blockF0 = blockIdx.x * 256;
    const int f = blockF0 + t;

    const int b       = blockF0 / PER_IMG4;       // image index
    const int localF0 = blockF0 % CHAN4;          // offset within channel
    const int h0      = localF0 / W4;             // first row this block touches

    __shared__ unsigned int rowbits[NROWS * 7];   // 6 rows x 7 words of bitmask

    if (t < NROWS * 7) rowbits[t] = 0u;

    // Issue the streaming load early; VMEM latency overlaps the mask build.
    vfloat4 v = imgs[f];

    __syncthreads();

    // Build: one patch per thread (N=98 < 256). Patch rows [x, x+16) clipped
    // to the block's window [h0, h0+6); set a 16-bit run starting at bit y.
    if (t < N) {
        int x = px[b * N + t];
        int y = py[b * N + t];
        int lo = x > h0 ? x : h0;
        int hi = (x + PP < h0 + NROWS) ? (x + PP) : (h0 + NROWS);
        if (lo < hi) {
            unsigned long long mm = 0xFFFFull << (y & 31);
            unsigned int lo32 = (unsigned int)mm;
            unsigned int hi32 = (unsigned int)(mm >> 32);
            int woff = y >> 5;
            for (int h = lo; h < hi; ++h) {
                int base = (h - h0) * 7 + woff;
                atomicOr(&rowbits[base], lo32);
                if (hi32) atomicOr(&rowbits[base + 1], hi32);
            }
        }
    }
    __syncthreads();

    // Apply: per-thread 4-bit mask from the LDS window.
    int lf = localF0 + t;
    int w4 = lf % W4;
    int h  = lf / W4;
    unsigned int word = rowbits[(h - h0) * 7 + (w4 >> 3)];
    unsigned int m4 = (word >> ((w4 & 7) * 4)) & 0xFu;
    if (m4 & 1u) v.x = 0.f;
    if (m4 & 2u) v.y = 0.f;
    if (m4 & 4u) v.z = 0.f;
    if (m4 & 8u) v.w = 0.f;
    __builtin_nontemporal_store(v, &out[f]);
}

extern "C" void kernel_launch(void* const* d_in, const int* in_sizes, int n_in,
                              void* d_out, int out_size, void* d_ws, size_t ws_size,
                              hipStream_t stream) {
    const float* imgs = (const float*)d_in[0];
    const int*   px   = (const int*)d_in[1];
    const int*   py   = (const int*)d_in[2];
    float*       out  = (float*)d_out;

    const int N = in_sizes[1] / BB;  // points per image (98)

    occl_fused<<<TOTAL4 / 256, 256, 0, stream>>>(
        (vfloat4*)out, (const vfloat4*)imgs, px, py, N);
}

// Round 6
// 134.650 us; speedup vs baseline: 1.0929x; 1.0226x over previous
//
#include <hip/hip_runtime.h>

// Problem constants (fixed by setup_inputs in the reference).
#define BB 128
#define CC 3
#define HH 224
#define WW 224
#define PP 16

#define W4 (WW / 4)               // 56 float4 per row
#define CHAN4 (HH * W4)           // 12544 float4 per channel = 49 * 256 (exact)
#define PER_IMG4 (CC * CHAN4)     // 37632 float4 per image
#define NROWS 6                   // 256 (h,w4) positions span at most 6 rows
#define NBLK (BB * (CHAN4 / 256)) // 128 * 49 = 6272 blocks

typedef float vfloat4 __attribute__((ext_vector_type(4)));

// ---------------------------------------------------------------------------
// Channel-fused: each block owns 256 (h,w4) positions of ONE image (mask is
// channel-invariant), builds a 6-row LDS bitmask from the point list, then
// streams all 3 channels at those positions. Mask build amortized 3x vs R5.
// Fully-masked float4s skip the global load entirely (exec-masked lanes)
// -> HW coalescer drops dead cache lines, trimming FETCH ~5-10%.
// ---------------------------------------------------------------------------
__global__ __launch_bounds__(256) void occl_fused(
        vfloat4* __restrict__ out, const vfloat4* __restrict__ imgs,
        const int* __restrict__ px, const int* __restrict__ py, int N) {
    const int t     = threadIdx.x;
    const int b     = blockIdx.x / (CHAN4 / 256);    // image index
    const int posF0 = (blockIdx.x % (CHAN4 / 256)) * 256;
    const int h0    = posF0 / W4;                    // first row in window

    __shared__ unsigned int rowbits[NROWS * 7];      // 6 rows x 7 mask words
    if (t < NROWS * 7) rowbits[t] = 0u;
    __syncthreads();

    // Build: one patch per thread (N=98 < 256), clipped to [h0, h0+6).
    if (t < N) {
        int x = px[b * N + t];
        int y = py[b * N + t];
        int lo = x > h0 ? x : h0;
        int hi = (x + PP < h0 + NROWS) ? (x + PP) : (h0 + NROWS);
        if (lo < hi) {
            unsigned long long mm = 0xFFFFull << (y & 31);
            unsigned int lo32 = (unsigned int)mm;
            unsigned int hi32 = (unsigned int)(mm >> 32);
            int woff = y >> 5;
            for (int h = lo; h < hi; ++h) {
                int base = (h - h0) * 7 + woff;
                atomicOr(&rowbits[base], lo32);
                if (hi32) atomicOr(&rowbits[base + 1], hi32);
            }
        }
    }
    __syncthreads();

    // Apply to all 3 channels at this (h,w4) position.
    int p  = posF0 + t;                 // position within channel [0, CHAN4)
    int w4 = p % W4;
    int h  = p / W4;
    unsigned int word = rowbits[(h - h0) * 7 + (w4 >> 3)];
    unsigned int m4 = (word >> ((w4 & 7) * 4)) & 0xFu;

    size_t f0 = (size_t)b * PER_IMG4 + p;            // channel 0
    vfloat4 z = {0.f, 0.f, 0.f, 0.f};
    vfloat4 v0 = z, v1 = z, v2 = z;
    if (m4 != 0xFu) {                    // skip loads where all 4 px masked
        v0 = __builtin_nontemporal_load(&imgs[f0]);
        v1 = __builtin_nontemporal_load(&imgs[f0 + CHAN4]);
        v2 = __builtin_nontemporal_load(&imgs[f0 + 2 * CHAN4]);
        if (m4 & 1u) { v0.x = 0.f; v1.x = 0.f; v2.x = 0.f; }
        if (m4 & 2u) { v0.y = 0.f; v1.y = 0.f; v2.y = 0.f; }
        if (m4 & 4u) { v0.z = 0.f; v1.z = 0.f; v2.z = 0.f; }
        if (m4 & 8u) { v0.w = 0.f; v1.w = 0.f; v2.w = 0.f; }
    }
    __builtin_nontemporal_store(v0, &out[f0]);
    __builtin_nontemporal_store(v1, &out[f0 + CHAN4]);
    __builtin_nontemporal_store(v2, &out[f0 + 2 * CHAN4]);
}

extern "C" void kernel_launch(void* const* d_in, const int* in_sizes, int n_in,
                              void* d_out, int out_size, void* d_ws, size_t ws_size,
                              hipStream_t stream) {
    const float* imgs = (const float*)d_in[0];
    const int*   px   = (const int*)d_in[1];
    const int*   py   = (const int*)d_in[2];
    float*       out  = (float*)d_out;

    const int N = in_sizes[1] / BB;  // points per image (98)

    occl_fused<<<NBLK, 256, 0, stream>>>(
        (vfloat4*)out, (const vfloat4*)imgs, px, py, N);
}